// Round 1
// baseline (9064.844 us; speedup 1.0000x reference)
//
#include <hip/hip_runtime.h>

#define HF 128
#define OUTF 16
#define NG 64
#define BN_EPS 1e-5f

// ---------------- degree / normalization ----------------

__global__ void deg_kernel(const int* __restrict__ dst, float* __restrict__ deg, int E) {
    int e = blockIdx.x * blockDim.x + threadIdx.x;
    if (e < E) atomicAdd(&deg[dst[e]], 1.0f);
}

__global__ void dis_kernel(float* __restrict__ deg, int n) {
    int i = blockIdx.x * blockDim.x + threadIdx.x;
    if (i < n) deg[i] = rsqrtf(deg[i] + 1.0f);   // +1 = self loop; always > 0
}

// ---------------- layer 0 expand: h2[i][j] = x[i] * W0[j] ----------------

__global__ void expand0_kernel(const float* __restrict__ x, const float* __restrict__ W0,
                               float* __restrict__ out, int n) {
    int idx = blockIdx.x * blockDim.x + threadIdx.x;
    if (idx < n * HF) {
        int i = idx >> 7, j = idx & 127;
        out[idx] = x[i] * W0[j];
    }
}

// ---------------- GEMM: C[n,128] = A[n,128] @ W[128,128] ----------------

__global__ __launch_bounds__(256) void gemm128_kernel(const float* __restrict__ A,
                                                      const float* __restrict__ W,
                                                      float* __restrict__ C, int n) {
    __shared__ float Ws[128 * 128];   // 64 KB, whole W
    __shared__ float As[16][128];     // 8 KB
    int t = threadIdx.x;
    for (int i = t; i < 128 * 128; i += 256) Ws[i] = W[i];
    int rowBase = blockIdx.x * 16;
    for (int i = t; i < 16 * 128; i += 256) {
        int r = rowBase + (i >> 7);
        As[i >> 7][i & 127] = (r < n) ? A[r * HF + (i & 127)] : 0.f;
    }
    __syncthreads();
    int jc = t & 31;    // float4 column chunk
    int rs = t >> 5;    // 0..7
    float4 acc0 = {0, 0, 0, 0}, acc1 = {0, 0, 0, 0};
    for (int k = 0; k < 128; ++k) {
        float4 w = reinterpret_cast<const float4*>(Ws + k * 128)[jc];
        float a0 = As[rs][k], a1 = As[rs + 8][k];
        acc0.x += a0 * w.x; acc0.y += a0 * w.y; acc0.z += a0 * w.z; acc0.w += a0 * w.w;
        acc1.x += a1 * w.x; acc1.y += a1 * w.y; acc1.z += a1 * w.z; acc1.w += a1 * w.w;
    }
    int r0 = rowBase + rs, r1 = r0 + 8;
    if (r0 < n) reinterpret_cast<float4*>(C + r0 * HF)[jc] = acc0;
    if (r1 < n) reinterpret_cast<float4*>(C + r1 * HF)[jc] = acc1;
}

// ---------------- edge scatter: agg[dst] += norm * h2[src] ----------------
// 32 consecutive threads per edge, 4 features each (float4 gather, 4 atomics)

__global__ void scatter_kernel(const float* __restrict__ h2, const float* __restrict__ dis,
                               const int* __restrict__ src, const int* __restrict__ dst,
                               float* __restrict__ agg, int E, int n) {
    int idx = blockIdx.x * blockDim.x + threadIdx.x;
    int total = (E + n) * 32;
    if (idx >= total) return;
    int e = idx >> 5;
    int c = (idx & 31) << 2;
    int s, d; float nrm;
    if (e < E) {
        s = src[e]; d = dst[e];
        nrm = dis[s] * dis[d];
    } else {
        s = d = e - E;
        float t = dis[s];
        nrm = t * t;       // self loop
    }
    float4 v = *reinterpret_cast<const float4*>(h2 + s * HF + c);
    float* a = agg + d * HF + c;
    atomicAdd(a + 0, v.x * nrm);
    atomicAdd(a + 1, v.y * nrm);
    atomicAdd(a + 2, v.z * nrm);
    atomicAdd(a + 3, v.w * nrm);
}

// ---------------- BN stats: per-column sum / sumsq ----------------

__global__ __launch_bounds__(256) void bn_stats_kernel(const float* __restrict__ a,
                                                       float* __restrict__ stats, int n) {
    int col = threadIdx.x & 127;
    int sub = threadIdx.x >> 7;   // 0/1
    float s = 0.f, ss = 0.f;
    for (int r = blockIdx.x * 2 + sub; r < n; r += gridDim.x * 2) {
        float v = a[r * HF + col];
        s += v; ss += v * v;
    }
    __shared__ float red[2][2][128];
    red[0][sub][col] = s;
    red[1][sub][col] = ss;
    __syncthreads();
    if (sub == 0) {
        atomicAdd(&stats[col],       red[0][0][col] + red[0][1][col]);
        atomicAdd(&stats[HF + col],  red[1][0][col] + red[1][1][col]);
    }
}

__global__ void bn_coef_kernel(const float* __restrict__ stats, const float* __restrict__ g,
                               const float* __restrict__ beta, float* __restrict__ coef,
                               float invn) {
    int j = threadIdx.x;
    if (j < HF) {
        float m = stats[j] * invn;
        float v = stats[HF + j] * invn - m * m;
        float sc = g[j] * rsqrtf(v + BN_EPS);
        coef[j] = sc;
        coef[HF + j] = beta[j] - m * sc;
    }
}

__global__ void bn_apply_kernel(float* __restrict__ a, const float* __restrict__ coef, int n) {
    int idx = blockIdx.x * blockDim.x + threadIdx.x;   // over n*H/4 float4s
    if (idx >= n * (HF / 4)) return;
    int jc = idx & 31;
    float4 sc = reinterpret_cast<const float4*>(coef)[jc];
    float4 sh = reinterpret_cast<const float4*>(coef + HF)[jc];
    float4 v = reinterpret_cast<float4*>(a)[idx];
    v.x = fmaxf(v.x * sc.x + sh.x, 0.f);
    v.y = fmaxf(v.y * sc.y + sh.y, 0.f);
    v.z = fmaxf(v.z * sc.z + sh.z, 0.f);
    v.w = fmaxf(v.w * sc.w + sh.w, 0.f);
    reinterpret_cast<float4*>(a)[idx] = v;
}

// ---------------- pooling ----------------

__global__ void starts_kernel(const int* __restrict__ batch, int* __restrict__ starts, int n) {
    int g = threadIdx.x;
    if (g > NG) return;
    int lo = 0, hi = n;
    while (lo < hi) {
        int mid = (lo + hi) >> 1;
        if (batch[mid] < g) lo = mid + 1; else hi = mid;
    }
    starts[g] = lo;
}

__global__ void pool_kernel(const float* __restrict__ h, const int* __restrict__ starts,
                            float* __restrict__ pooled) {
    int g = blockIdx.x >> 4;
    int p = blockIdx.x & 15;
    int col = threadIdx.x;   // 128
    int s = starts[g], e = starts[g + 1];
    int len = e - s;
    int chunk = (len + 15) >> 4;
    int r0 = s + p * chunk;
    int r1 = min(e, r0 + chunk);
    float acc = 0.f;
    for (int r = r0; r < r1; ++r) acc += h[r * HF + col];
    if (r1 > r0) atomicAdd(&pooled[g * HF + col], acc);
}

// ---------------- head: relu(pooled/cnt @ Wl + bl) @ Wo + bo ----------------

__global__ __launch_bounds__(1024) void head_kernel(const float* __restrict__ pooled,
                                                    const int* __restrict__ starts,
                                                    const float* __restrict__ Wl,
                                                    const float* __restrict__ bl,
                                                    const float* __restrict__ Wo,
                                                    const float* __restrict__ bo,
                                                    float* __restrict__ out) {
    __shared__ float P[NG][HF];
    __shared__ float T[NG][HF];
    int t = threadIdx.x;
    for (int i = t; i < NG * HF; i += 1024) {
        int g = i >> 7;
        float cnt = fmaxf((float)(starts[g + 1] - starts[g]), 1.0f);
        P[g][i & 127] = pooled[i] / cnt;
    }
    __syncthreads();
    for (int i = t; i < NG * HF; i += 1024) {
        int g = i >> 7, j = i & 127;
        float acc = bl[j];
        for (int k = 0; k < HF; ++k) acc += P[g][k] * Wl[k * HF + j];
        T[g][j] = fmaxf(acc, 0.f);
    }
    __syncthreads();
    int g = t >> 4, o = t & 15;
    float acc = bo[o];
    for (int k = 0; k < HF; ++k) acc += T[g][k] * Wo[k * OUTF + o];
    out[t] = acc;
}

// ---------------- launch ----------------

extern "C" void kernel_launch(void* const* d_in, const int* in_sizes, int n_in,
                              void* d_out, int out_size, void* d_ws, size_t ws_size,
                              hipStream_t stream) {
    const float* x     = (const float*)d_in[0];
    const int*   ei    = (const int*)d_in[1];
    const int*   batch = (const int*)d_in[2];
    const float* W0 = (const float*)d_in[3];
    const float* g0 = (const float*)d_in[5];
    const float* be0 = (const float*)d_in[6];
    const float* W1 = (const float*)d_in[7];
    const float* g1 = (const float*)d_in[9];
    const float* be1 = (const float*)d_in[10];
    const float* W2 = (const float*)d_in[11];
    const float* g2 = (const float*)d_in[13];
    const float* be2 = (const float*)d_in[14];
    const float* Wl = (const float*)d_in[15];
    const float* bl = (const float*)d_in[16];
    const float* Wo = (const float*)d_in[17];
    const float* bo = (const float*)d_in[18];

    const int n = in_sizes[0];        // 100000
    const int E = in_sizes[1] / 2;    // 1600000
    const int* srcI = ei;
    const int* dstI = ei + E;

    float* bufA  = (float*)d_ws;                 // n*H
    float* bufB  = bufA + (size_t)n * HF;        // n*H
    float* dis   = bufB + (size_t)n * HF;        // n
    float* stats = dis + n;                      // 2*H
    float* coef  = stats + 2 * HF;               // 2*H
    float* pooled = coef + 2 * HF;               // NG*H
    int*   starts = (int*)(pooled + NG * HF);    // NG+1

    const float* Ws[3]   = {W0, W1, W2};
    const float* gs[3]   = {g0, g1, g2};
    const float* betas[3] = {be0, be1, be2};

    // degree -> dis
    hipMemsetAsync(dis, 0, (size_t)n * 4, stream);
    deg_kernel<<<(E + 255) / 256, 256, 0, stream>>>(dstI, dis, E);
    dis_kernel<<<(n + 255) / 256, 256, 0, stream>>>(dis, n);

    int scatterBlocks = ((E + n) * 32 + 255) / 256;
    for (int layer = 0; layer < 3; ++layer) {
        if (layer == 0) {
            expand0_kernel<<<(n * HF + 255) / 256, 256, 0, stream>>>(x, W0, bufB, n);
        } else {
            gemm128_kernel<<<(n + 15) / 16, 256, 0, stream>>>(bufA, Ws[layer], bufB, n);
        }
        hipMemsetAsync(bufA, 0, (size_t)n * HF * 4, stream);
        scatter_kernel<<<scatterBlocks, 256, 0, stream>>>(bufB, dis, srcI, dstI, bufA, E, n);
        hipMemsetAsync(stats, 0, 2 * HF * 4, stream);
        bn_stats_kernel<<<512, 256, 0, stream>>>(bufA, stats, n);
        bn_coef_kernel<<<1, 128, 0, stream>>>(stats, gs[layer], betas[layer], coef, 1.0f / n);
        bn_apply_kernel<<<(n * (HF / 4) + 255) / 256, 256, 0, stream>>>(bufA, coef, n);
    }

    starts_kernel<<<1, 128, 0, stream>>>(batch, starts, n);
    hipMemsetAsync(pooled, 0, NG * HF * 4, stream);
    pool_kernel<<<NG * 16, 128, 0, stream>>>(bufA, starts, pooled);
    head_kernel<<<1, 1024, 0, stream>>>(pooled, starts, Wl, bl, Wo, bo, (float*)d_out);
}

// Round 2
// 982.514 us; speedup vs baseline: 9.2262x; 9.2262x over previous
//
#include <hip/hip_runtime.h>

#define HF 128
#define OUTF 16
#define NG 64
#define BN_EPS 1e-5f

// ---------------- degree (int) / normalization ----------------

__global__ void degi_kernel(const int* __restrict__ dst, int* __restrict__ degi, int E) {
    int e = blockIdx.x * blockDim.x + threadIdx.x;
    if (e < E) atomicAdd(&degi[dst[e]], 1);
}

__global__ void dis_kernel(const int* __restrict__ degi, float* __restrict__ dis, int n) {
    int i = blockIdx.x * blockDim.x + threadIdx.x;
    if (i < n) dis[i] = rsqrtf((float)degi[i] + 1.0f);   // +1 = self loop
}

// ---------------- prefix sum (rowptr over deg+1) ----------------

__global__ __launch_bounds__(256) void scan_partial(const int* __restrict__ degi,
                                                    int* __restrict__ blocksums, int n) {
    __shared__ int sdata[256];
    int b = blockIdx.x, t = threadIdx.x;
    int s = 0;
    for (int k = t; k < 1024; k += 256) {
        int i = b * 1024 + k;
        if (i < n) s += degi[i] + 1;
    }
    sdata[t] = s; __syncthreads();
    for (int o = 128; o > 0; o >>= 1) {
        if (t < o) sdata[t] += sdata[t + o];
        __syncthreads();
    }
    if (t == 0) blocksums[b] = sdata[0];
}

__global__ void scan_sums(int* __restrict__ blocksums, int nb) {
    if (threadIdx.x == 0) {
        int run = 0;
        for (int i = 0; i < nb; ++i) { int v = blocksums[i]; blocksums[i] = run; run += v; }
    }
}

__global__ __launch_bounds__(256) void scan_final(const int* __restrict__ degi,
                                                  const int* __restrict__ blocksums,
                                                  int* __restrict__ rowptr, int n) {
    int b = blockIdx.x, t = threadIdx.x;
    int base = b * 1024 + t * 4;
    int v[4]; int s = 0;
    for (int k = 0; k < 4; ++k) {
        int i = base + k;
        v[k] = (i < n) ? degi[i] + 1 : 0;
        s += v[k];
    }
    __shared__ int ts[256];
    ts[t] = s; __syncthreads();
    for (int o = 1; o < 256; o <<= 1) {
        int val = (t >= o) ? ts[t - o] : 0;
        __syncthreads();
        ts[t] += val;
        __syncthreads();
    }
    int off = blocksums[b] + ((t > 0) ? ts[t - 1] : 0);
    for (int k = 0; k < 4; ++k) {
        int i = base + k;
        if (i < n) {
            rowptr[i] = off;
            off += v[k];
            if (i == n - 1) rowptr[n] = off;
        }
    }
}

__global__ void copy_cursor(const int* __restrict__ rowptr, int* __restrict__ cursor, int n) {
    int i = blockIdx.x * blockDim.x + threadIdx.x;
    if (i < n) cursor[i] = rowptr[i];
}

// ---------------- CSR fill ----------------

__global__ void fill_kernel(const int* __restrict__ src, const int* __restrict__ dst,
                            const float* __restrict__ dis, int* __restrict__ cursor,
                            int* __restrict__ csr_src, float* __restrict__ csr_w, int E) {
    int e = blockIdx.x * blockDim.x + threadIdx.x;
    if (e < E) {
        int s = src[e], d = dst[e];
        int pos = atomicAdd(&cursor[d], 1);
        csr_src[pos] = s;
        csr_w[pos] = dis[s] * dis[d];
    }
}

__global__ void fill_self_kernel(const float* __restrict__ dis, int* __restrict__ cursor,
                                 int* __restrict__ csr_src, float* __restrict__ csr_w, int n) {
    int i = blockIdx.x * blockDim.x + threadIdx.x;
    if (i < n) {
        int pos = atomicAdd(&cursor[i], 1);
        csr_src[pos] = i;
        float t = dis[i];
        csr_w[pos] = t * t;
    }
}

// ---------------- layer 0: scalar gather + scalar BN stats ----------------

__global__ void gather1_kernel(const float* __restrict__ x, const int* __restrict__ rowptr,
                               const int* __restrict__ csr_src, const float* __restrict__ csr_w,
                               float* __restrict__ aggx, int n) {
    int i = blockIdx.x * blockDim.x + threadIdx.x;
    if (i >= n) return;
    float acc = 0.f;
    int e = rowptr[i + 1];
    for (int j = rowptr[i]; j < e; ++j) acc += csr_w[j] * x[csr_src[j]];
    aggx[i] = acc;
}

__global__ void stats1_kernel(const float* __restrict__ aggx, float* __restrict__ stats1, int n) {
    float s = 0.f, ss = 0.f;
    for (int i = blockIdx.x * blockDim.x + threadIdx.x; i < n; i += gridDim.x * blockDim.x) {
        float v = aggx[i]; s += v; ss += v * v;
    }
    for (int o = 32; o > 0; o >>= 1) { s += __shfl_down(s, o); ss += __shfl_down(ss, o); }
    if ((threadIdx.x & 63) == 0) { atomicAdd(&stats1[0], s); atomicAdd(&stats1[1], ss); }
}

__global__ void coef0_kernel(const float* __restrict__ stats1, const float* __restrict__ W0,
                             const float* __restrict__ g, const float* __restrict__ beta,
                             float* __restrict__ coef, float invn) {
    int j = threadIdx.x;
    if (j < HF) {
        float m = stats1[0] * invn;
        float var = stats1[1] * invn - m * m;
        float w = W0[j];
        float sc = g[j] * w * rsqrtf(var * w * w + BN_EPS);
        coef[j] = sc;
        coef[HF + j] = beta[j] - m * sc;
    }
}

__global__ void h0_kernel(const float* __restrict__ aggx, const float* __restrict__ coef,
                          float* __restrict__ h0, int n) {
    int idx = blockIdx.x * blockDim.x + threadIdx.x;   // n*32 float4s
    if (idx >= n * (HF / 4)) return;
    int i = idx >> 5, jc = idx & 31;
    float a = aggx[i];
    float4 sc = reinterpret_cast<const float4*>(coef)[jc];
    float4 sh = reinterpret_cast<const float4*>(coef + HF)[jc];
    float4 o;
    o.x = fmaxf(a * sc.x + sh.x, 0.f);
    o.y = fmaxf(a * sc.y + sh.y, 0.f);
    o.z = fmaxf(a * sc.z + sh.z, 0.f);
    o.w = fmaxf(a * sc.w + sh.w, 0.f);
    reinterpret_cast<float4*>(h0)[idx] = o;
}

// ---------------- GEMM: C[n,128] = A[n,128] @ W[128,128] ----------------

__global__ __launch_bounds__(256) void gemm128_kernel(const float* __restrict__ A,
                                                      const float* __restrict__ W,
                                                      float* __restrict__ C, int n) {
    __shared__ float Ws[128 * 128];
    __shared__ float As[16][128];
    int t = threadIdx.x;
    for (int i = t; i < 128 * 128; i += 256) Ws[i] = W[i];
    int rowBase = blockIdx.x * 16;
    for (int i = t; i < 16 * 128; i += 256) {
        int r = rowBase + (i >> 7);
        As[i >> 7][i & 127] = (r < n) ? A[r * HF + (i & 127)] : 0.f;
    }
    __syncthreads();
    int jc = t & 31;
    int rs = t >> 5;
    float4 acc0 = {0, 0, 0, 0}, acc1 = {0, 0, 0, 0};
    for (int k = 0; k < 128; ++k) {
        float4 w = reinterpret_cast<const float4*>(Ws + k * 128)[jc];
        float a0 = As[rs][k], a1 = As[rs + 8][k];
        acc0.x += a0 * w.x; acc0.y += a0 * w.y; acc0.z += a0 * w.z; acc0.w += a0 * w.w;
        acc1.x += a1 * w.x; acc1.y += a1 * w.y; acc1.z += a1 * w.z; acc1.w += a1 * w.w;
    }
    int r0 = rowBase + rs, r1 = r0 + 8;
    if (r0 < n) reinterpret_cast<float4*>(C + r0 * HF)[jc] = acc0;
    if (r1 < n) reinterpret_cast<float4*>(C + r1 * HF)[jc] = acc1;
}

// ---------------- CSR gather, H=128: wave per node ----------------

__global__ __launch_bounds__(256) void gather128_kernel(const float* __restrict__ h2,
                                                        const int* __restrict__ rowptr,
                                                        const int* __restrict__ csr_src,
                                                        const float* __restrict__ csr_w,
                                                        float* __restrict__ agg, int n) {
    int node = (blockIdx.x * 256 + threadIdx.x) >> 6;
    int lane = threadIdx.x & 63;
    if (node >= n) return;
    int beg = rowptr[node], end = rowptr[node + 1];
    float2 acc = {0.f, 0.f};
    for (int j = beg; j < end; ++j) {
        int s = csr_src[j];
        float w = csr_w[j];
        float2 v = *reinterpret_cast<const float2*>(h2 + s * HF + lane * 2);
        acc.x += v.x * w;
        acc.y += v.y * w;
    }
    *reinterpret_cast<float2*>(agg + node * HF + lane * 2) = acc;
}

// ---------------- BN stats / coef / apply ----------------

__global__ __launch_bounds__(256) void bn_stats_kernel(const float* __restrict__ a,
                                                       float* __restrict__ stats, int n) {
    int col = threadIdx.x & 127;
    int sub = threadIdx.x >> 7;
    float s = 0.f, ss = 0.f;
    for (int r = blockIdx.x * 2 + sub; r < n; r += gridDim.x * 2) {
        float v = a[r * HF + col];
        s += v; ss += v * v;
    }
    __shared__ float red[2][2][128];
    red[0][sub][col] = s;
    red[1][sub][col] = ss;
    __syncthreads();
    if (sub == 0) {
        atomicAdd(&stats[col],      red[0][0][col] + red[0][1][col]);
        atomicAdd(&stats[HF + col], red[1][0][col] + red[1][1][col]);
    }
}

__global__ void bn_coef_kernel(const float* __restrict__ stats, const float* __restrict__ g,
                               const float* __restrict__ beta, float* __restrict__ coef,
                               float invn) {
    int j = threadIdx.x;
    if (j < HF) {
        float m = stats[j] * invn;
        float v = stats[HF + j] * invn - m * m;
        float sc = g[j] * rsqrtf(v + BN_EPS);
        coef[j] = sc;
        coef[HF + j] = beta[j] - m * sc;
    }
}

__global__ void bn_apply_kernel(float* __restrict__ a, const float* __restrict__ coef, int n) {
    int idx = blockIdx.x * blockDim.x + threadIdx.x;
    if (idx >= n * (HF / 4)) return;
    int jc = idx & 31;
    float4 sc = reinterpret_cast<const float4*>(coef)[jc];
    float4 sh = reinterpret_cast<const float4*>(coef + HF)[jc];
    float4 v = reinterpret_cast<float4*>(a)[idx];
    v.x = fmaxf(v.x * sc.x + sh.x, 0.f);
    v.y = fmaxf(v.y * sc.y + sh.y, 0.f);
    v.z = fmaxf(v.z * sc.z + sh.z, 0.f);
    v.w = fmaxf(v.w * sc.w + sh.w, 0.f);
    reinterpret_cast<float4*>(a)[idx] = v;
}

// ---------------- pooling ----------------

__global__ void starts_kernel(const int* __restrict__ batch, int* __restrict__ starts, int n) {
    int g = threadIdx.x;
    if (g > NG) return;
    int lo = 0, hi = n;
    while (lo < hi) {
        int mid = (lo + hi) >> 1;
        if (batch[mid] < g) lo = mid + 1; else hi = mid;
    }
    starts[g] = lo;
}

__global__ void pool_kernel(const float* __restrict__ h, const int* __restrict__ starts,
                            float* __restrict__ pooled) {
    int g = blockIdx.x >> 4;
    int p = blockIdx.x & 15;
    int col = threadIdx.x;
    int s = starts[g], e = starts[g + 1];
    int len = e - s;
    int chunk = (len + 15) >> 4;
    int r0 = s + p * chunk;
    int r1 = min(e, r0 + chunk);
    float acc = 0.f;
    for (int r = r0; r < r1; ++r) acc += h[r * HF + col];
    if (r1 > r0) atomicAdd(&pooled[g * HF + col], acc);
}

// ---------------- head ----------------

__global__ __launch_bounds__(1024) void head_kernel(const float* __restrict__ pooled,
                                                    const int* __restrict__ starts,
                                                    const float* __restrict__ Wl,
                                                    const float* __restrict__ bl,
                                                    const float* __restrict__ Wo,
                                                    const float* __restrict__ bo,
                                                    float* __restrict__ out) {
    __shared__ float P[NG][HF];
    __shared__ float T[NG][HF];
    int t = threadIdx.x;
    for (int i = t; i < NG * HF; i += 1024) {
        int g = i >> 7;
        float cnt = fmaxf((float)(starts[g + 1] - starts[g]), 1.0f);
        P[g][i & 127] = pooled[i] / cnt;
    }
    __syncthreads();
    for (int i = t; i < NG * HF; i += 1024) {
        int g = i >> 7, j = i & 127;
        float acc = bl[j];
        for (int k = 0; k < HF; ++k) acc += P[g][k] * Wl[k * HF + j];
        T[g][j] = fmaxf(acc, 0.f);
    }
    __syncthreads();
    int g = t >> 4, o = t & 15;
    float acc = bo[o];
    for (int k = 0; k < HF; ++k) acc += T[g][k] * Wo[k * OUTF + o];
    out[t] = acc;
}

// ---------------- launch ----------------

extern "C" void kernel_launch(void* const* d_in, const int* in_sizes, int n_in,
                              void* d_out, int out_size, void* d_ws, size_t ws_size,
                              hipStream_t stream) {
    const float* x     = (const float*)d_in[0];
    const int*   ei    = (const int*)d_in[1];
    const int*   batch = (const int*)d_in[2];
    const float* W0 = (const float*)d_in[3];
    const float* g0 = (const float*)d_in[5];
    const float* be0 = (const float*)d_in[6];
    const float* W1 = (const float*)d_in[7];
    const float* g1 = (const float*)d_in[9];
    const float* be1 = (const float*)d_in[10];
    const float* W2 = (const float*)d_in[11];
    const float* g2 = (const float*)d_in[13];
    const float* be2 = (const float*)d_in[14];
    const float* Wl = (const float*)d_in[15];
    const float* bl = (const float*)d_in[16];
    const float* Wo = (const float*)d_in[17];
    const float* bo = (const float*)d_in[18];

    const int n = in_sizes[0];
    const int E = in_sizes[1] / 2;
    const int* srcI = ei;
    const int* dstI = ei + E;
    const int M = E + n;               // CSR entries incl. self loops

    float* bufA   = (float*)d_ws;                    // n*HF
    float* bufB   = bufA + (size_t)n * HF;           // n*HF
    float* dis    = bufB + (size_t)n * HF;           // n
    float* csr_w  = dis + n;                         // M
    float* aggx   = csr_w + M;                       // n
    float* stats  = aggx + n;                        // 2*HF (+2 scalar at [256],[257])
    float* coef   = stats + 2 * HF + 2;              // 2*HF
    float* pooled = coef + 2 * HF;                   // NG*HF
    int* degi     = (int*)(pooled + NG * HF);        // n
    int* rowptr   = degi + n;                        // n+1
    int* cursor   = rowptr + n + 1;                  // n
    int* csr_src  = cursor + n;                      // M
    int* blocksums = csr_src + M;                    // scan blocks
    int* starts   = blocksums + 256;                 // NG+1

    float* stats1 = stats + 2 * HF;                  // 2 scalars

    const int nbScan = (n + 1023) / 1024;

    // ---- CSR build ----
    hipMemsetAsync(degi, 0, (size_t)n * 4, stream);
    degi_kernel<<<(E + 255) / 256, 256, 0, stream>>>(dstI, degi, E);
    dis_kernel<<<(n + 255) / 256, 256, 0, stream>>>(degi, dis, n);
    scan_partial<<<nbScan, 256, 0, stream>>>(degi, blocksums, n);
    scan_sums<<<1, 64, 0, stream>>>(blocksums, nbScan);
    scan_final<<<nbScan, 256, 0, stream>>>(degi, blocksums, rowptr, n);
    copy_cursor<<<(n + 255) / 256, 256, 0, stream>>>(rowptr, cursor, n);
    fill_kernel<<<(E + 255) / 256, 256, 0, stream>>>(srcI, dstI, dis, cursor, csr_src, csr_w, E);
    fill_self_kernel<<<(n + 255) / 256, 256, 0, stream>>>(dis, cursor, csr_src, csr_w, n);

    // ---- layer 0 (rank-1) ----
    gather1_kernel<<<(n + 255) / 256, 256, 0, stream>>>(x, rowptr, csr_src, csr_w, aggx, n);
    hipMemsetAsync(stats1, 0, 2 * 4, stream);
    stats1_kernel<<<256, 256, 0, stream>>>(aggx, stats1, n);
    coef0_kernel<<<1, 128, 0, stream>>>(stats1, W0, g0, be0, coef, 1.0f / n);
    h0_kernel<<<(n * 32 + 255) / 256, 256, 0, stream>>>(aggx, coef, bufA, n);

    // ---- layers 1, 2 ----
    const float* Ws[3]    = {W0, W1, W2};
    const float* gs[3]    = {g0, g1, g2};
    const float* betas[3] = {be0, be1, be2};
    for (int layer = 1; layer < 3; ++layer) {
        gemm128_kernel<<<(n + 15) / 16, 256, 0, stream>>>(bufA, Ws[layer], bufB, n);
        gather128_kernel<<<(n * 64 + 255) / 256, 256, 0, stream>>>(bufB, rowptr, csr_src, csr_w, bufA, n);
        hipMemsetAsync(stats, 0, 2 * HF * 4, stream);
        bn_stats_kernel<<<512, 256, 0, stream>>>(bufA, stats, n);
        bn_coef_kernel<<<1, 128, 0, stream>>>(stats, gs[layer], betas[layer], coef, 1.0f / n);
        bn_apply_kernel<<<(n * 32 + 255) / 256, 256, 0, stream>>>(bufA, coef, n);
    }

    // ---- pool + head ----
    starts_kernel<<<1, 128, 0, stream>>>(batch, starts, n);
    hipMemsetAsync(pooled, 0, NG * HF * 4, stream);
    pool_kernel<<<NG * 16, 128, 0, stream>>>(bufA, starts, pooled);
    head_kernel<<<1, 1024, 0, stream>>>(pooled, starts, Wl, bl, Wo, bo, (float*)d_out);
}

// Round 3
// 846.925 us; speedup vs baseline: 10.7032x; 1.1601x over previous
//
#include <hip/hip_runtime.h>

#define HF 128
#define OUTF 16
#define NG 64
#define BN_EPS 1e-5f

typedef unsigned short ushortT;
typedef unsigned int uintT;

__device__ __forceinline__ float bf2f(uintT u) {
    union { uintT i; float f; } c; c.i = u << 16; return c.f;
}
__device__ __forceinline__ uintT f2bf(float f) {
    union { float f; uintT i; } c; c.f = f;
    uintT u = c.i;
    return (u + 0x7fffu + ((u >> 16) & 1u)) >> 16;
}
__device__ __forceinline__ uintT pack2(float a, float b) {
    return f2bf(a) | (f2bf(b) << 16);
}

// ---------------- degree (int) / normalization ----------------

__global__ void degi_kernel(const int* __restrict__ dst, int* __restrict__ degi, int E) {
    int e = blockIdx.x * blockDim.x + threadIdx.x;
    if (e < E) atomicAdd(&degi[dst[e]], 1);
}

__global__ void dis_kernel(const int* __restrict__ degi, float* __restrict__ dis, int n) {
    int i = blockIdx.x * blockDim.x + threadIdx.x;
    if (i < n) dis[i] = rsqrtf((float)degi[i] + 1.0f);   // +1 = self loop
}

// ---------------- prefix sum (rowptr over deg+1) ----------------

__global__ __launch_bounds__(256) void scan_partial(const int* __restrict__ degi,
                                                    int* __restrict__ blocksums, int n) {
    __shared__ int sdata[256];
    int b = blockIdx.x, t = threadIdx.x;
    int s = 0;
    for (int k = t; k < 1024; k += 256) {
        int i = b * 1024 + k;
        if (i < n) s += degi[i] + 1;
    }
    sdata[t] = s; __syncthreads();
    for (int o = 128; o > 0; o >>= 1) {
        if (t < o) sdata[t] += sdata[t + o];
        __syncthreads();
    }
    if (t == 0) blocksums[b] = sdata[0];
}

__global__ void scan_sums(int* __restrict__ blocksums, int nb) {
    if (threadIdx.x == 0) {
        int run = 0;
        for (int i = 0; i < nb; ++i) { int v = blocksums[i]; blocksums[i] = run; run += v; }
    }
}

__global__ __launch_bounds__(256) void scan_final(const int* __restrict__ degi,
                                                  const int* __restrict__ blocksums,
                                                  int* __restrict__ rowptr, int n) {
    int b = blockIdx.x, t = threadIdx.x;
    int base = b * 1024 + t * 4;
    int v[4]; int s = 0;
    for (int k = 0; k < 4; ++k) {
        int i = base + k;
        v[k] = (i < n) ? degi[i] + 1 : 0;
        s += v[k];
    }
    __shared__ int ts[256];
    ts[t] = s; __syncthreads();
    for (int o = 1; o < 256; o <<= 1) {
        int val = (t >= o) ? ts[t - o] : 0;
        __syncthreads();
        ts[t] += val;
        __syncthreads();
    }
    int off = blocksums[b] + ((t > 0) ? ts[t - 1] : 0);
    for (int k = 0; k < 4; ++k) {
        int i = base + k;
        if (i < n) {
            rowptr[i] = off;
            off += v[k];
            if (i == n - 1) rowptr[n] = off;
        }
    }
}

__global__ void copy_cursor(const int* __restrict__ rowptr, int* __restrict__ cursor, int n) {
    int i = blockIdx.x * blockDim.x + threadIdx.x;
    if (i < n) cursor[i] = rowptr[i];
}

// ---------------- CSR fill ----------------

__global__ void fill_kernel(const int* __restrict__ src, const int* __restrict__ dst,
                            const float* __restrict__ dis, int* __restrict__ cursor,
                            int* __restrict__ csr_src, float* __restrict__ csr_w, int E) {
    int e = blockIdx.x * blockDim.x + threadIdx.x;
    if (e < E) {
        int s = src[e], d = dst[e];
        int pos = atomicAdd(&cursor[d], 1);
        csr_src[pos] = s;
        csr_w[pos] = dis[s] * dis[d];
    }
}

__global__ void fill_self_kernel(const float* __restrict__ dis, int* __restrict__ cursor,
                                 int* __restrict__ csr_src, float* __restrict__ csr_w, int n) {
    int i = blockIdx.x * blockDim.x + threadIdx.x;
    if (i < n) {
        int pos = atomicAdd(&cursor[i], 1);
        csr_src[pos] = i;
        float t = dis[i];
        csr_w[pos] = t * t;
    }
}

// ---------------- layer 0: scalar gather + scalar BN stats ----------------

__global__ void gather1_kernel(const float* __restrict__ x, const int* __restrict__ rowptr,
                               const int* __restrict__ csr_src, const float* __restrict__ csr_w,
                               float* __restrict__ aggx, int n) {
    int i = blockIdx.x * blockDim.x + threadIdx.x;
    if (i >= n) return;
    float acc = 0.f;
    int e = rowptr[i + 1];
    for (int j = rowptr[i]; j < e; ++j) acc += csr_w[j] * x[csr_src[j]];
    aggx[i] = acc;
}

__global__ void stats1_kernel(const float* __restrict__ aggx, float* __restrict__ stats1, int n) {
    float s = 0.f, ss = 0.f;
    for (int i = blockIdx.x * blockDim.x + threadIdx.x; i < n; i += gridDim.x * blockDim.x) {
        float v = aggx[i]; s += v; ss += v * v;
    }
    for (int o = 32; o > 0; o >>= 1) { s += __shfl_down(s, o); ss += __shfl_down(ss, o); }
    if ((threadIdx.x & 63) == 0) { atomicAdd(&stats1[0], s); atomicAdd(&stats1[1], ss); }
}

__global__ void coef0_kernel(const float* __restrict__ stats1, const float* __restrict__ W0,
                             const float* __restrict__ g, const float* __restrict__ beta,
                             float* __restrict__ coef, float invn) {
    int j = threadIdx.x;
    if (j < HF) {
        float m = stats1[0] * invn;
        float var = stats1[1] * invn - m * m;
        float w = W0[j];
        float sc = g[j] * w * rsqrtf(var * w * w + BN_EPS);
        coef[j] = sc;
        coef[HF + j] = beta[j] - m * sc;
    }
}

__global__ void h0_kernel(const float* __restrict__ aggx, const float* __restrict__ coef,
                          ushortT* __restrict__ h0, int n) {
    int idx = blockIdx.x * blockDim.x + threadIdx.x;   // n*32 groups of 4 cols
    if (idx >= n * (HF / 4)) return;
    int i = idx >> 5, jc = idx & 31;
    float a = aggx[i];
    float4 sc = reinterpret_cast<const float4*>(coef)[jc];
    float4 sh = reinterpret_cast<const float4*>(coef + HF)[jc];
    float o0 = fmaxf(a * sc.x + sh.x, 0.f);
    float o1 = fmaxf(a * sc.y + sh.y, 0.f);
    float o2 = fmaxf(a * sc.z + sh.z, 0.f);
    float o3 = fmaxf(a * sc.w + sh.w, 0.f);
    uint2 o; o.x = pack2(o0, o1); o.y = pack2(o2, o3);
    reinterpret_cast<uint2*>(h0)[idx] = o;
}

// ---------------- GEMM: C[n,128] = A[n,128] @ W[128,128], bf16 in/out ----------------

__global__ __launch_bounds__(256) void gemm128_kernel(const ushortT* __restrict__ A,
                                                      const float* __restrict__ W,
                                                      ushortT* __restrict__ C, int n) {
    __shared__ float Ws[128 * 128];
    __shared__ float As[16][128];
    int t = threadIdx.x;
    for (int i = t; i < 128 * 128; i += 256) Ws[i] = W[i];
    int rowBase = blockIdx.x * 16;
    for (int i = t; i < 16 * 32; i += 256) {
        int rr = i >> 5, g = i & 31;
        int r = rowBase + rr;
        uint2 v = make_uint2(0u, 0u);
        if (r < n) v = *reinterpret_cast<const uint2*>(A + (size_t)r * HF + g * 4);
        As[rr][g * 4 + 0] = bf2f(v.x & 0xffff);
        As[rr][g * 4 + 1] = bf2f(v.x >> 16);
        As[rr][g * 4 + 2] = bf2f(v.y & 0xffff);
        As[rr][g * 4 + 3] = bf2f(v.y >> 16);
    }
    __syncthreads();
    int jc = t & 31;
    int rs = t >> 5;
    float4 acc0 = {0, 0, 0, 0}, acc1 = {0, 0, 0, 0};
    for (int k = 0; k < 128; ++k) {
        float4 w = reinterpret_cast<const float4*>(Ws + k * 128)[jc];
        float a0 = As[rs][k], a1 = As[rs + 8][k];
        acc0.x += a0 * w.x; acc0.y += a0 * w.y; acc0.z += a0 * w.z; acc0.w += a0 * w.w;
        acc1.x += a1 * w.x; acc1.y += a1 * w.y; acc1.z += a1 * w.z; acc1.w += a1 * w.w;
    }
    int r0 = rowBase + rs, r1 = r0 + 8;
    if (r0 < n) {
        uint2 o; o.x = pack2(acc0.x, acc0.y); o.y = pack2(acc0.z, acc0.w);
        *reinterpret_cast<uint2*>(C + (size_t)r0 * HF + jc * 4) = o;
    }
    if (r1 < n) {
        uint2 o; o.x = pack2(acc1.x, acc1.y); o.y = pack2(acc1.z, acc1.w);
        *reinterpret_cast<uint2*>(C + (size_t)r1 * HF + jc * 4) = o;
    }
}

// ---------------- CSR gather, H=128 bf16: wave per node ----------------

__global__ __launch_bounds__(256) void gather128_kernel(const ushortT* __restrict__ h2,
                                                        const int* __restrict__ rowptr,
                                                        const int* __restrict__ csr_src,
                                                        const float* __restrict__ csr_w,
                                                        ushortT* __restrict__ agg, int n) {
    int node = (blockIdx.x * 256 + threadIdx.x) >> 6;
    int lane = threadIdx.x & 63;
    if (node >= n) return;
    int beg = rowptr[node], end = rowptr[node + 1];
    float a0 = 0.f, a1 = 0.f;
    for (int base = beg; base < end; base += 64) {
        int idx = base + lane;
        int sj = (idx < end) ? csr_src[idx] : 0;
        float wj = (idx < end) ? csr_w[idx] : 0.f;
        int cnt = min(64, end - base);
        #pragma unroll 2
        for (int j = 0; j < cnt; ++j) {
            int s = __shfl(sj, j);
            float w = __shfl(wj, j);
            uintT v = *reinterpret_cast<const uintT*>(h2 + (size_t)s * HF + lane * 2);
            a0 += bf2f(v & 0xffff) * w;
            a1 += bf2f(v >> 16) * w;
        }
    }
    *reinterpret_cast<uintT*>(agg + (size_t)node * HF + lane * 2) = pack2(a0, a1);
}

// ---------------- BN stats / coef / apply (bf16 data) ----------------

__global__ __launch_bounds__(256) void bn_stats_kernel(const ushortT* __restrict__ a,
                                                       float* __restrict__ stats, int n) {
    int lane = threadIdx.x & 63;     // cols 2*lane, 2*lane+1
    int sub = threadIdx.x >> 6;      // 0..3
    float s0 = 0.f, s1 = 0.f, ss0 = 0.f, ss1 = 0.f;
    for (int r = blockIdx.x * 4 + sub; r < n; r += gridDim.x * 4) {
        uintT v = *reinterpret_cast<const uintT*>(a + (size_t)r * HF + lane * 2);
        float x0 = bf2f(v & 0xffff), x1 = bf2f(v >> 16);
        s0 += x0; ss0 += x0 * x0;
        s1 += x1; ss1 += x1 * x1;
    }
    __shared__ float red[4][4][64];
    red[0][sub][lane] = s0; red[1][sub][lane] = s1;
    red[2][sub][lane] = ss0; red[3][sub][lane] = ss1;
    __syncthreads();
    if (sub == 0) {
        float S0 = red[0][0][lane] + red[0][1][lane] + red[0][2][lane] + red[0][3][lane];
        float S1 = red[1][0][lane] + red[1][1][lane] + red[1][2][lane] + red[1][3][lane];
        float T0 = red[2][0][lane] + red[2][1][lane] + red[2][2][lane] + red[2][3][lane];
        float T1 = red[3][0][lane] + red[3][1][lane] + red[3][2][lane] + red[3][3][lane];
        atomicAdd(&stats[lane * 2], S0);
        atomicAdd(&stats[lane * 2 + 1], S1);
        atomicAdd(&stats[HF + lane * 2], T0);
        atomicAdd(&stats[HF + lane * 2 + 1], T1);
    }
}

__global__ void bn_coef_kernel(const float* __restrict__ stats, const float* __restrict__ g,
                               const float* __restrict__ beta, float* __restrict__ coef,
                               float invn) {
    int j = threadIdx.x;
    if (j < HF) {
        float m = stats[j] * invn;
        float v = stats[HF + j] * invn - m * m;
        float sc = g[j] * rsqrtf(v + BN_EPS);
        coef[j] = sc;
        coef[HF + j] = beta[j] - m * sc;
    }
}

__global__ void bn_apply_kernel(ushortT* __restrict__ a, const float* __restrict__ coef, int n) {
    int idx = blockIdx.x * blockDim.x + threadIdx.x;
    if (idx >= n * (HF / 4)) return;
    int jc = idx & 31;
    float4 sc = reinterpret_cast<const float4*>(coef)[jc];
    float4 sh = reinterpret_cast<const float4*>(coef + HF)[jc];
    uint2 v = reinterpret_cast<uint2*>(a)[idx];
    float o0 = fmaxf(bf2f(v.x & 0xffff) * sc.x + sh.x, 0.f);
    float o1 = fmaxf(bf2f(v.x >> 16)    * sc.y + sh.y, 0.f);
    float o2 = fmaxf(bf2f(v.y & 0xffff) * sc.z + sh.z, 0.f);
    float o3 = fmaxf(bf2f(v.y >> 16)    * sc.w + sh.w, 0.f);
    uint2 o; o.x = pack2(o0, o1); o.y = pack2(o2, o3);
    reinterpret_cast<uint2*>(a)[idx] = o;
}

// ---------------- pooling ----------------

__global__ void starts_kernel(const int* __restrict__ batch, int* __restrict__ starts, int n) {
    int g = threadIdx.x;
    if (g > NG) return;
    int lo = 0, hi = n;
    while (lo < hi) {
        int mid = (lo + hi) >> 1;
        if (batch[mid] < g) lo = mid + 1; else hi = mid;
    }
    starts[g] = lo;
}

__global__ void pool_kernel(const ushortT* __restrict__ h, const int* __restrict__ starts,
                            float* __restrict__ pooled) {
    int g = blockIdx.x >> 4;
    int p = blockIdx.x & 15;
    int lane = threadIdx.x;          // 64: cols 2*lane, 2*lane+1
    int s = starts[g], e = starts[g + 1];
    int len = e - s;
    int chunk = (len + 15) >> 4;
    int r0 = s + p * chunk;
    int r1 = min(e, r0 + chunk);
    float a0 = 0.f, a1 = 0.f;
    for (int r = r0; r < r1; ++r) {
        uintT v = *reinterpret_cast<const uintT*>(h + (size_t)r * HF + lane * 2);
        a0 += bf2f(v & 0xffff);
        a1 += bf2f(v >> 16);
    }
    if (r1 > r0) {
        atomicAdd(&pooled[g * HF + lane * 2], a0);
        atomicAdd(&pooled[g * HF + lane * 2 + 1], a1);
    }
}

// ---------------- head ----------------

__global__ __launch_bounds__(1024) void head_kernel(const float* __restrict__ pooled,
                                                    const int* __restrict__ starts,
                                                    const float* __restrict__ Wl,
                                                    const float* __restrict__ bl,
                                                    const float* __restrict__ Wo,
                                                    const float* __restrict__ bo,
                                                    float* __restrict__ out) {
    __shared__ float P[NG][HF];
    __shared__ float T[NG][HF];
    int t = threadIdx.x;
    for (int i = t; i < NG * HF; i += 1024) {
        int g = i >> 7;
        float cnt = fmaxf((float)(starts[g + 1] - starts[g]), 1.0f);
        P[g][i & 127] = pooled[i] / cnt;
    }
    __syncthreads();
    for (int i = t; i < NG * HF; i += 1024) {
        int g = i >> 7, j = i & 127;
        float acc = bl[j];
        for (int k = 0; k < HF; ++k) acc += P[g][k] * Wl[k * HF + j];
        T[g][j] = fmaxf(acc, 0.f);
    }
    __syncthreads();
    int g = t >> 4, o = t & 15;
    float acc = bo[o];
    for (int k = 0; k < HF; ++k) acc += T[g][k] * Wo[k * OUTF + o];
    out[t] = acc;
}

// ---------------- launch ----------------

extern "C" void kernel_launch(void* const* d_in, const int* in_sizes, int n_in,
                              void* d_out, int out_size, void* d_ws, size_t ws_size,
                              hipStream_t stream) {
    const float* x     = (const float*)d_in[0];
    const int*   ei    = (const int*)d_in[1];
    const int*   batch = (const int*)d_in[2];
    const float* W0 = (const float*)d_in[3];
    const float* g0 = (const float*)d_in[5];
    const float* be0 = (const float*)d_in[6];
    const float* W1 = (const float*)d_in[7];
    const float* g1 = (const float*)d_in[9];
    const float* be1 = (const float*)d_in[10];
    const float* W2 = (const float*)d_in[11];
    const float* g2 = (const float*)d_in[13];
    const float* be2 = (const float*)d_in[14];
    const float* Wl = (const float*)d_in[15];
    const float* bl = (const float*)d_in[16];
    const float* Wo = (const float*)d_in[17];
    const float* bo = (const float*)d_in[18];

    const int n = in_sizes[0];
    const int E = in_sizes[1] / 2;
    const int* srcI = ei;
    const int* dstI = ei + E;
    const int M = E + n;

    ushortT* bufA = (ushortT*)d_ws;                      // n*HF bf16
    ushortT* bufB = bufA + (size_t)n * HF;               // n*HF bf16
    float* dis    = (float*)(bufB + (size_t)n * HF);     // n
    float* csr_w  = dis + n;                             // M
    float* aggx   = csr_w + M;                           // n
    float* stats  = aggx + n;                            // 2*HF + 2
    float* coef   = stats + 2 * HF + 2;                  // 2*HF
    float* pooled = coef + 2 * HF;                       // NG*HF
    int* degi     = (int*)(pooled + NG * HF);            // n
    int* rowptr   = degi + n;                            // n+1
    int* cursor   = rowptr + n + 1;                      // n
    int* csr_src  = cursor + n;                          // M
    int* blocksums = csr_src + M;                        // 256
    int* starts   = blocksums + 256;                     // NG+1
    float* stats1 = stats + 2 * HF;                      // 2 scalars

    const int nbScan = (n + 1023) / 1024;

    // ---- CSR build ----
    hipMemsetAsync(degi, 0, (size_t)n * 4, stream);
    degi_kernel<<<(E + 255) / 256, 256, 0, stream>>>(dstI, degi, E);
    dis_kernel<<<(n + 255) / 256, 256, 0, stream>>>(degi, dis, n);
    scan_partial<<<nbScan, 256, 0, stream>>>(degi, blocksums, n);
    scan_sums<<<1, 64, 0, stream>>>(blocksums, nbScan);
    scan_final<<<nbScan, 256, 0, stream>>>(degi, blocksums, rowptr, n);
    copy_cursor<<<(n + 255) / 256, 256, 0, stream>>>(rowptr, cursor, n);
    fill_kernel<<<(E + 255) / 256, 256, 0, stream>>>(srcI, dstI, dis, cursor, csr_src, csr_w, E);
    fill_self_kernel<<<(n + 255) / 256, 256, 0, stream>>>(dis, cursor, csr_src, csr_w, n);

    // ---- layer 0 (rank-1) ----
    gather1_kernel<<<(n + 255) / 256, 256, 0, stream>>>(x, rowptr, csr_src, csr_w, aggx, n);
    hipMemsetAsync(stats1, 0, 2 * 4, stream);
    stats1_kernel<<<256, 256, 0, stream>>>(aggx, stats1, n);
    coef0_kernel<<<1, 128, 0, stream>>>(stats1, W0, g0, be0, coef, 1.0f / n);
    h0_kernel<<<(n * 32 + 255) / 256, 256, 0, stream>>>(aggx, coef, bufA, n);

    // ---- layers 1, 2 ----
    const float* Ws[3]    = {W0, W1, W2};
    const float* gs[3]    = {g0, g1, g2};
    const float* betas[3] = {be0, be1, be2};
    for (int layer = 1; layer < 3; ++layer) {
        gemm128_kernel<<<(n + 15) / 16, 256, 0, stream>>>(bufA, Ws[layer], bufB, n);
        gather128_kernel<<<(n * 64 + 255) / 256, 256, 0, stream>>>(bufB, rowptr, csr_src, csr_w, bufA, n);
        hipMemsetAsync(stats, 0, 2 * HF * 4, stream);
        bn_stats_kernel<<<512, 256, 0, stream>>>(bufA, stats, n);
        bn_coef_kernel<<<1, 128, 0, stream>>>(stats, gs[layer], betas[layer], coef, 1.0f / n);
        bn_apply_kernel<<<(n * 32 + 255) / 256, 256, 0, stream>>>(bufA, coef, n);
    }

    // ---- pool + head ----
    starts_kernel<<<1, 128, 0, stream>>>(batch, starts, n);
    hipMemsetAsync(pooled, 0, NG * HF * 4, stream);
    pool_kernel<<<NG * 16, 64, 0, stream>>>(bufA, starts, pooled);
    head_kernel<<<1, 1024, 0, stream>>>(pooled, starts, Wl, bl, Wo, bo, (float*)d_out);
}

// Round 4
// 729.360 us; speedup vs baseline: 12.4285x; 1.1612x over previous
//
#include <hip/hip_runtime.h>

#define HF 128
#define OUTF 16
#define NG 64
#define BN_EPS 1e-5f

typedef unsigned short ushortT;
typedef unsigned int uintT;

__device__ __forceinline__ float bf2f(uintT u) {
    union { uintT i; float f; } c; c.i = u << 16; return c.f;
}
__device__ __forceinline__ float bf2f_hi(uintT u) {
    union { uintT i; float f; } c; c.i = u & 0xffff0000u; return c.f;
}
__device__ __forceinline__ uintT f2bf(float f) {
    union { float f; uintT i; } c; c.f = f;
    uintT u = c.i;
    return (u + 0x7fffu + ((u >> 16) & 1u)) >> 16;
}
__device__ __forceinline__ uintT pack2(float a, float b) {
    return f2bf(a) | (f2bf(b) << 16);
}

// ---------------- degree (int) / normalization ----------------

__global__ void degi_kernel(const int* __restrict__ dst, int* __restrict__ degi, int E) {
    int e = blockIdx.x * blockDim.x + threadIdx.x;
    if (e < E) atomicAdd(&degi[dst[e]], 1);
}

__global__ void dis_xp_kernel(const int* __restrict__ degi, const float* __restrict__ x,
                              float* __restrict__ dis, float* __restrict__ xp, int n) {
    int i = blockIdx.x * blockDim.x + threadIdx.x;
    if (i < n) {
        float d = rsqrtf((float)degi[i] + 1.0f);   // +1 = self loop
        dis[i] = d;
        xp[i] = d * x[i];
    }
}

// ---------------- prefix sum (rowptr over deg; no self-loop entries) ----------------

__global__ __launch_bounds__(256) void scan_partial(const int* __restrict__ degi,
                                                    int* __restrict__ blocksums, int n) {
    __shared__ int sdata[256];
    int b = blockIdx.x, t = threadIdx.x;
    int s = 0;
    for (int k = t; k < 1024; k += 256) {
        int i = b * 1024 + k;
        if (i < n) s += degi[i];
    }
    sdata[t] = s; __syncthreads();
    for (int o = 128; o > 0; o >>= 1) {
        if (t < o) sdata[t] += sdata[t + o];
        __syncthreads();
    }
    if (t == 0) blocksums[b] = sdata[0];
}

__global__ void scan_sums(int* __restrict__ blocksums, int nb) {
    if (threadIdx.x == 0) {
        int run = 0;
        for (int i = 0; i < nb; ++i) { int v = blocksums[i]; blocksums[i] = run; run += v; }
    }
}

__global__ __launch_bounds__(256) void scan_final(const int* __restrict__ degi,
                                                  const int* __restrict__ blocksums,
                                                  int* __restrict__ rowptr, int n) {
    int b = blockIdx.x, t = threadIdx.x;
    int base = b * 1024 + t * 4;
    int v[4]; int s = 0;
    for (int k = 0; k < 4; ++k) {
        int i = base + k;
        v[k] = (i < n) ? degi[i] : 0;
        s += v[k];
    }
    __shared__ int ts[256];
    ts[t] = s; __syncthreads();
    for (int o = 1; o < 256; o <<= 1) {
        int val = (t >= o) ? ts[t - o] : 0;
        __syncthreads();
        ts[t] += val;
        __syncthreads();
    }
    int off = blocksums[b] + ((t > 0) ? ts[t - 1] : 0);
    for (int k = 0; k < 4; ++k) {
        int i = base + k;
        if (i < n) {
            rowptr[i] = off;
            off += v[k];
            if (i == n - 1) rowptr[n] = off;
        }
    }
}

__global__ void copy_cursor(const int* __restrict__ rowptr, int* __restrict__ cursor, int n) {
    int i = blockIdx.x * blockDim.x + threadIdx.x;
    if (i < n) cursor[i] = rowptr[i];
}

// ---------------- CSR fill (src index only) ----------------

__global__ void fill_kernel(const int* __restrict__ src, const int* __restrict__ dst,
                            int* __restrict__ cursor, int* __restrict__ csr_src, int E) {
    int e = blockIdx.x * blockDim.x + threadIdx.x;
    if (e < E) {
        int s = src[e], d = dst[e];
        int pos = atomicAdd(&cursor[d], 1);
        csr_src[pos] = s;
    }
}

// ---------------- layer 0: scalar gather (xp = dis*x) ----------------

__global__ void gather1_kernel(const float* __restrict__ xp, const int* __restrict__ rowptr,
                               const int* __restrict__ csr_src, const float* __restrict__ dis,
                               float* __restrict__ aggx, int n) {
    int i = blockIdx.x * blockDim.x + threadIdx.x;
    if (i >= n) return;
    float acc = xp[i];                // self loop
    int e = rowptr[i + 1];
    for (int j = rowptr[i]; j < e; ++j) acc += xp[csr_src[j]];
    aggx[i] = acc * dis[i];
}

__global__ void stats1_kernel(const float* __restrict__ aggx, float* __restrict__ stats1, int n) {
    float s = 0.f, ss = 0.f;
    for (int i = blockIdx.x * blockDim.x + threadIdx.x; i < n; i += gridDim.x * blockDim.x) {
        float v = aggx[i]; s += v; ss += v * v;
    }
    for (int o = 32; o > 0; o >>= 1) { s += __shfl_down(s, o); ss += __shfl_down(ss, o); }
    if ((threadIdx.x & 63) == 0) { atomicAdd(&stats1[0], s); atomicAdd(&stats1[1], ss); }
}

__global__ void coef0_kernel(const float* __restrict__ stats1, const float* __restrict__ W0,
                             const float* __restrict__ g, const float* __restrict__ beta,
                             float* __restrict__ coef, float invn) {
    int j = threadIdx.x;
    if (j < HF) {
        float m = stats1[0] * invn;
        float var = stats1[1] * invn - m * m;
        float w = W0[j];
        float sc = g[j] * w * rsqrtf(var * w * w + BN_EPS);
        coef[j] = sc;
        coef[HF + j] = beta[j] - m * sc;
    }
}

__global__ void h0_kernel(const float* __restrict__ aggx, const float* __restrict__ coef,
                          ushortT* __restrict__ h0, int n) {
    int idx = blockIdx.x * blockDim.x + threadIdx.x;
    if (idx >= n * (HF / 4)) return;
    int i = idx >> 5, jc = idx & 31;
    float a = aggx[i];
    float4 sc = reinterpret_cast<const float4*>(coef)[jc];
    float4 sh = reinterpret_cast<const float4*>(coef + HF)[jc];
    float o0 = fmaxf(a * sc.x + sh.x, 0.f);
    float o1 = fmaxf(a * sc.y + sh.y, 0.f);
    float o2 = fmaxf(a * sc.z + sh.z, 0.f);
    float o3 = fmaxf(a * sc.w + sh.w, 0.f);
    uint2 o; o.x = pack2(o0, o1); o.y = pack2(o2, o3);
    reinterpret_cast<uint2*>(h0)[idx] = o;
}

// ---------------- GEMM: C[n,128] = dis[row] * (act(A)[n,128] @ W[128,128]) ----------------
// applyCoef: A is pre-BN; apply relu(v*coef[c]+coef[HF+c]) during LDS staging.

__global__ __launch_bounds__(256) void gemm128_kernel(const ushortT* __restrict__ A,
                                                      const float* __restrict__ W,
                                                      const float* __restrict__ coef,
                                                      const float* __restrict__ dis,
                                                      ushortT* __restrict__ C, int n,
                                                      int applyCoef) {
    __shared__ float Ws[128 * 128];
    __shared__ float As[16][128];
    int t = threadIdx.x;
    for (int i = t; i < 128 * 128; i += 256) Ws[i] = W[i];
    int rowBase = blockIdx.x * 16;
    for (int i = t; i < 16 * 32; i += 256) {
        int rr = i >> 5, g = i & 31;
        int r = rowBase + rr;
        uint2 v = make_uint2(0u, 0u);
        if (r < n) v = *reinterpret_cast<const uint2*>(A + (size_t)r * HF + g * 4);
        float f0 = bf2f(v.x & 0xffff), f1 = bf2f_hi(v.x);
        float f2 = bf2f(v.y & 0xffff), f3 = bf2f_hi(v.y);
        if (applyCoef) {
            int c = g * 4;
            f0 = fmaxf(f0 * coef[c + 0] + coef[HF + c + 0], 0.f);
            f1 = fmaxf(f1 * coef[c + 1] + coef[HF + c + 1], 0.f);
            f2 = fmaxf(f2 * coef[c + 2] + coef[HF + c + 2], 0.f);
            f3 = fmaxf(f3 * coef[c + 3] + coef[HF + c + 3], 0.f);
        }
        As[rr][g * 4 + 0] = f0;
        As[rr][g * 4 + 1] = f1;
        As[rr][g * 4 + 2] = f2;
        As[rr][g * 4 + 3] = f3;
    }
    __syncthreads();
    int jc = t & 31;
    int rs = t >> 5;
    float4 acc0 = {0, 0, 0, 0}, acc1 = {0, 0, 0, 0};
    for (int k = 0; k < 128; ++k) {
        float4 w = reinterpret_cast<const float4*>(Ws + k * 128)[jc];
        float a0 = As[rs][k], a1 = As[rs + 8][k];
        acc0.x += a0 * w.x; acc0.y += a0 * w.y; acc0.z += a0 * w.z; acc0.w += a0 * w.w;
        acc1.x += a1 * w.x; acc1.y += a1 * w.y; acc1.z += a1 * w.z; acc1.w += a1 * w.w;
    }
    int r0 = rowBase + rs, r1 = r0 + 8;
    if (r0 < n) {
        float d0 = dis[r0];
        uint2 o; o.x = pack2(acc0.x * d0, acc0.y * d0); o.y = pack2(acc0.z * d0, acc0.w * d0);
        *reinterpret_cast<uint2*>(C + (size_t)r0 * HF + jc * 4) = o;
    }
    if (r1 < n) {
        float d1 = dis[r1];
        uint2 o; o.x = pack2(acc1.x * d1, acc1.y * d1); o.y = pack2(acc1.z * d1, acc1.w * d1);
        *reinterpret_cast<uint2*>(C + (size_t)r1 * HF + jc * 4) = o;
    }
}

// ---------------- CSR gather, no weights: agg[d] = dis[d]*(sum rows + own row) ----------------

__global__ __launch_bounds__(256) void gather128_kernel(const ushortT* __restrict__ h2,
                                                        const int* __restrict__ rowptr,
                                                        const int* __restrict__ csr_src,
                                                        const float* __restrict__ dis,
                                                        ushortT* __restrict__ agg, int n) {
    int node = (blockIdx.x * 256 + threadIdx.x) >> 6;
    int lane = threadIdx.x & 63;
    if (node >= n) return;
    int beg = rowptr[node], end = rowptr[node + 1];
    // self loop: own (pre-scaled) row
    uintT vs = *reinterpret_cast<const uintT*>(h2 + (size_t)node * HF + lane * 2);
    float a0 = bf2f(vs & 0xffff), a1 = bf2f_hi(vs);
    for (int base = beg; base < end; base += 64) {
        int idx = base + lane;
        int sj = (idx < end) ? csr_src[idx] : 0;
        int cnt = min(64, end - base);
        int j = 0;
        for (; j + 4 <= cnt; j += 4) {
            int s0 = __shfl(sj, j);
            int s1 = __shfl(sj, j + 1);
            int s2 = __shfl(sj, j + 2);
            int s3 = __shfl(sj, j + 3);
            uintT v0 = *reinterpret_cast<const uintT*>(h2 + (size_t)s0 * HF + lane * 2);
            uintT v1 = *reinterpret_cast<const uintT*>(h2 + (size_t)s1 * HF + lane * 2);
            uintT v2 = *reinterpret_cast<const uintT*>(h2 + (size_t)s2 * HF + lane * 2);
            uintT v3 = *reinterpret_cast<const uintT*>(h2 + (size_t)s3 * HF + lane * 2);
            a0 += bf2f(v0 & 0xffff); a1 += bf2f_hi(v0);
            a0 += bf2f(v1 & 0xffff); a1 += bf2f_hi(v1);
            a0 += bf2f(v2 & 0xffff); a1 += bf2f_hi(v2);
            a0 += bf2f(v3 & 0xffff); a1 += bf2f_hi(v3);
        }
        for (; j < cnt; ++j) {
            int s = __shfl(sj, j);
            uintT v = *reinterpret_cast<const uintT*>(h2 + (size_t)s * HF + lane * 2);
            a0 += bf2f(v & 0xffff); a1 += bf2f_hi(v);
        }
    }
    float dd = dis[node];
    *reinterpret_cast<uintT*>(agg + (size_t)node * HF + lane * 2) = pack2(a0 * dd, a1 * dd);
}

// ---------------- BN stats / coef ----------------

__global__ __launch_bounds__(256) void bn_stats_kernel(const ushortT* __restrict__ a,
                                                       float* __restrict__ stats, int n) {
    int lane = threadIdx.x & 63;
    int sub = threadIdx.x >> 6;
    float s0 = 0.f, s1 = 0.f, ss0 = 0.f, ss1 = 0.f;
    for (int r = blockIdx.x * 4 + sub; r < n; r += gridDim.x * 4) {
        uintT v = *reinterpret_cast<const uintT*>(a + (size_t)r * HF + lane * 2);
        float x0 = bf2f(v & 0xffff), x1 = bf2f_hi(v);
        s0 += x0; ss0 += x0 * x0;
        s1 += x1; ss1 += x1 * x1;
    }
    __shared__ float red[4][4][64];
    red[0][sub][lane] = s0; red[1][sub][lane] = s1;
    red[2][sub][lane] = ss0; red[3][sub][lane] = ss1;
    __syncthreads();
    if (sub == 0) {
        float S0 = red[0][0][lane] + red[0][1][lane] + red[0][2][lane] + red[0][3][lane];
        float S1 = red[1][0][lane] + red[1][1][lane] + red[1][2][lane] + red[1][3][lane];
        float T0 = red[2][0][lane] + red[2][1][lane] + red[2][2][lane] + red[2][3][lane];
        float T1 = red[3][0][lane] + red[3][1][lane] + red[3][2][lane] + red[3][3][lane];
        atomicAdd(&stats[lane * 2], S0);
        atomicAdd(&stats[lane * 2 + 1], S1);
        atomicAdd(&stats[HF + lane * 2], T0);
        atomicAdd(&stats[HF + lane * 2 + 1], T1);
    }
}

__global__ void bn_coef_kernel(const float* __restrict__ stats, const float* __restrict__ g,
                               const float* __restrict__ beta, float* __restrict__ coef,
                               float invn) {
    int j = threadIdx.x;
    if (j < HF) {
        float m = stats[j] * invn;
        float v = stats[HF + j] * invn - m * m;
        float sc = g[j] * rsqrtf(v + BN_EPS);
        coef[j] = sc;
        coef[HF + j] = beta[j] - m * sc;
    }
}

// ---------------- pooling (fused BN+ReLU of layer 2) ----------------

__global__ void starts_kernel(const int* __restrict__ batch, int* __restrict__ starts, int n) {
    int g = threadIdx.x;
    if (g > NG) return;
    int lo = 0, hi = n;
    while (lo < hi) {
        int mid = (lo + hi) >> 1;
        if (batch[mid] < g) lo = mid + 1; else hi = mid;
    }
    starts[g] = lo;
}

__global__ void pool_kernel(const ushortT* __restrict__ h, const float* __restrict__ coef,
                            const int* __restrict__ starts, float* __restrict__ pooled) {
    int g = blockIdx.x >> 4;
    int p = blockIdx.x & 15;
    int lane = threadIdx.x;          // 64: cols 2*lane, 2*lane+1
    float sc0 = coef[lane * 2],     sc1 = coef[lane * 2 + 1];
    float sh0 = coef[HF + lane * 2], sh1 = coef[HF + lane * 2 + 1];
    int s = starts[g], e = starts[g + 1];
    int len = e - s;
    int chunk = (len + 15) >> 4;
    int r0 = s + p * chunk;
    int r1 = min(e, r0 + chunk);
    float a0 = 0.f, a1 = 0.f;
    for (int r = r0; r < r1; ++r) {
        uintT v = *reinterpret_cast<const uintT*>(h + (size_t)r * HF + lane * 2);
        a0 += fmaxf(bf2f(v & 0xffff) * sc0 + sh0, 0.f);
        a1 += fmaxf(bf2f_hi(v) * sc1 + sh1, 0.f);
    }
    if (r1 > r0) {
        atomicAdd(&pooled[g * HF + lane * 2], a0);
        atomicAdd(&pooled[g * HF + lane * 2 + 1], a1);
    }
}

// ---------------- head ----------------

__global__ __launch_bounds__(1024) void head_kernel(const float* __restrict__ pooled,
                                                    const int* __restrict__ starts,
                                                    const float* __restrict__ Wl,
                                                    const float* __restrict__ bl,
                                                    const float* __restrict__ Wo,
                                                    const float* __restrict__ bo,
                                                    float* __restrict__ out) {
    __shared__ float P[NG][HF];
    __shared__ float T[NG][HF];
    int t = threadIdx.x;
    for (int i = t; i < NG * HF; i += 1024) {
        int g = i >> 7;
        float cnt = fmaxf((float)(starts[g + 1] - starts[g]), 1.0f);
        P[g][i & 127] = pooled[i] / cnt;
    }
    __syncthreads();
    for (int i = t; i < NG * HF; i += 1024) {
        int g = i >> 7, j = i & 127;
        float acc = bl[j];
        for (int k = 0; k < HF; ++k) acc += P[g][k] * Wl[k * HF + j];
        T[g][j] = fmaxf(acc, 0.f);
    }
    __syncthreads();
    int g = t >> 4, o = t & 15;
    float acc = bo[o];
    for (int k = 0; k < HF; ++k) acc += T[g][k] * Wo[k * OUTF + o];
    out[t] = acc;
}

// ---------------- launch ----------------

extern "C" void kernel_launch(void* const* d_in, const int* in_sizes, int n_in,
                              void* d_out, int out_size, void* d_ws, size_t ws_size,
                              hipStream_t stream) {
    const float* x     = (const float*)d_in[0];
    const int*   ei    = (const int*)d_in[1];
    const int*   batch = (const int*)d_in[2];
    const float* W0 = (const float*)d_in[3];
    const float* g0 = (const float*)d_in[5];
    const float* be0 = (const float*)d_in[6];
    const float* W1 = (const float*)d_in[7];
    const float* g1 = (const float*)d_in[9];
    const float* be1 = (const float*)d_in[10];
    const float* W2 = (const float*)d_in[11];
    const float* g2 = (const float*)d_in[13];
    const float* be2 = (const float*)d_in[14];
    const float* Wl = (const float*)d_in[15];
    const float* bl = (const float*)d_in[16];
    const float* Wo = (const float*)d_in[17];
    const float* bo = (const float*)d_in[18];

    const int n = in_sizes[0];
    const int E = in_sizes[1] / 2;
    const int* srcI = ei;
    const int* dstI = ei + E;

    ushortT* bufA = (ushortT*)d_ws;                      // n*HF bf16
    ushortT* bufB = bufA + (size_t)n * HF;               // n*HF bf16
    float* dis    = (float*)(bufB + (size_t)n * HF);     // n
    float* xp     = dis + n;                             // n
    float* aggx   = xp + n;                              // n
    float* stats  = aggx + n;                            // 2*HF + 2
    float* coef   = stats + 2 * HF + 2;                  // 2*HF
    float* pooled = coef + 2 * HF;                       // NG*HF
    int* degi     = (int*)(pooled + NG * HF);            // n
    int* rowptr   = degi + n;                            // n+1
    int* cursor   = rowptr + n + 1;                      // n
    int* csr_src  = cursor + n;                          // E
    int* blocksums = csr_src + E;                        // 256
    int* starts   = blocksums + 256;                     // NG+1
    float* stats1 = stats + 2 * HF;                      // 2 scalars

    const int nbScan = (n + 1023) / 1024;

    // ---- CSR build (src-only, no self loops) ----
    hipMemsetAsync(degi, 0, (size_t)n * 4, stream);
    degi_kernel<<<(E + 255) / 256, 256, 0, stream>>>(dstI, degi, E);
    dis_xp_kernel<<<(n + 255) / 256, 256, 0, stream>>>(degi, x, dis, xp, n);
    scan_partial<<<nbScan, 256, 0, stream>>>(degi, blocksums, n);
    scan_sums<<<1, 64, 0, stream>>>(blocksums, nbScan);
    scan_final<<<nbScan, 256, 0, stream>>>(degi, blocksums, rowptr, n);
    copy_cursor<<<(n + 255) / 256, 256, 0, stream>>>(rowptr, cursor, n);
    fill_kernel<<<(E + 255) / 256, 256, 0, stream>>>(srcI, dstI, cursor, csr_src, E);

    // ---- layer 0 (rank-1) ----
    gather1_kernel<<<(n + 255) / 256, 256, 0, stream>>>(xp, rowptr, csr_src, dis, aggx, n);
    hipMemsetAsync(stats1, 0, 2 * 4, stream);
    stats1_kernel<<<256, 256, 0, stream>>>(aggx, stats1, n);
    coef0_kernel<<<1, 128, 0, stream>>>(stats1, W0, g0, be0, coef, 1.0f / n);
    h0_kernel<<<(n * 32 + 255) / 256, 256, 0, stream>>>(aggx, coef, bufA, n);

    // ---- layer 1: t1' = dis*(h0@W1); agg1 = gather; coef1 ----
    gemm128_kernel<<<(n + 15) / 16, 256, 0, stream>>>(bufA, W1, coef, dis, bufB, n, 0);
    gather128_kernel<<<(n * 64 + 255) / 256, 256, 0, stream>>>(bufB, rowptr, csr_src, dis, bufA, n);
    hipMemsetAsync(stats, 0, 2 * HF * 4, stream);
    bn_stats_kernel<<<512, 256, 0, stream>>>(bufA, stats, n);
    bn_coef_kernel<<<1, 128, 0, stream>>>(stats, g1, be1, coef, 1.0f / n);

    // ---- layer 2: apply coef1 in GEMM A-load; t2' = dis*(h1@W2); agg2; coef2 ----
    gemm128_kernel<<<(n + 15) / 16, 256, 0, stream>>>(bufA, W2, coef, dis, bufB, n, 1);
    gather128_kernel<<<(n * 64 + 255) / 256, 256, 0, stream>>>(bufB, rowptr, csr_src, dis, bufA, n);
    hipMemsetAsync(stats, 0, 2 * HF * 4, stream);
    bn_stats_kernel<<<512, 256, 0, stream>>>(bufA, stats, n);
    bn_coef_kernel<<<1, 128, 0, stream>>>(stats, g2, be2, coef, 1.0f / n);

    // ---- pool (fused BN+ReLU) + head ----
    starts_kernel<<<1, 128, 0, stream>>>(batch, starts, n);
    hipMemsetAsync(pooled, 0, NG * HF * 4, stream);
    pool_kernel<<<NG * 16, 64, 0, stream>>>(bufA, coef, starts, pooled);
    head_kernel<<<1, 1024, 0, stream>>>(pooled, starts, Wl, bl, Wo, bo, (float*)d_out);
}